// Round 1
// baseline (6764.109 us; speedup 1.0000x reference)
//
#include <hip/hip_runtime.h>
#include <hip/hip_bf16.h>
#include <math.h>

// ---------------- problem constants ----------------
#define QLEN 256
#define MLEN 256
#define KLEN 512
#define BSZ 8
#define DMODEL 1024
#define NHEAD 16
#define DHEAD 64
#define DINNER 4096
#define NTOKEN 32000
#define NLAYER 2
#define NTOKENS_TOT 2048   // QLEN*BSZ
#define VTILES 500         // 32000/64

// ---------------- workspace layout (float offsets) ----------------
// h:    2,097,152   cat: 4,194,304   wh: 12,582,912 (aliases t1 8,388,608 + t2 2,097,152)
// pos:  524,288     rhk: 524,288     prob: 16,777,216 (aliases pmax/psum/lse/tgt)
// vec:  2,097,152   -> total 38,797,312 floats = 155.2 MB
static const size_t O_H    = 0;
static const size_t O_CAT  = 2097152;
static const size_t O_WH   = O_CAT + 4194304;       // size 12,582,912
static const size_t O_T1   = O_WH;                  // 2048*4096
static const size_t O_T2   = O_WH + 8388608;        // 2048*1024
static const size_t O_POS  = O_WH + 12582912;       // 512*1024
static const size_t O_RHK  = O_POS + 524288;        // 512*1024
static const size_t O_PROB = O_RHK + 524288;        // 256*8*16*512
static const size_t O_PMAX = O_PROB;                // 2048*500
static const size_t O_PSUM = O_PROB + 1024000;      // 2048*500
static const size_t O_LSE  = O_PROB + 2048000;      // 2048
static const size_t O_TGT  = O_LSE + 2048;          // 2048
static const size_t O_VEC  = O_PROB + 16777216;     // 2048*1024

// ---------------- kernels ----------------

// h[t][d] = vocab_emb[dec_inp[t]][d] * 32
__global__ __launch_bounds__(256) void embed_kernel(const int* __restrict__ dec,
    const float* __restrict__ emb, float* __restrict__ h) {
    int t = blockIdx.x;
    int tok = dec[t];
    const float* src = emb + (size_t)tok * DMODEL;
    float* dst = h + (size_t)t * DMODEL;
    for (int u = 0; u < 4; ++u) {
        int d = threadIdx.x + u * 256;
        dst[d] = src[d] * 32.0f;
    }
}

// pos_emb[r][0:512]=sin(pos*invfreq), [512:1024]=cos(...)  pos = 511 - r
__global__ __launch_bounds__(256) void posemb_kernel(float* __restrict__ pe) {
    int r = blockIdx.x;
    float pos = (float)(KLEN - 1 - r);
    for (int u = 0; u < 2; ++u) {
        int dp = threadIdx.x + u * 256;  // 0..511
        float inv = expf(-(float)dp * (9.210340371976184f / 512.0f)); // ln(10000)/512
        float ang = pos * inv;
        pe[(size_t)r * DMODEL + dp]        = sinf(ang);
        pe[(size_t)r * DMODEL + 512 + dp]  = cosf(ang);
    }
}

// cat[0:2M] = mems[l], cat[2M:4M] = h
__global__ __launch_bounds__(256) void cat_kernel(const float* __restrict__ mem,
    const float* __restrict__ h, float* __restrict__ cat) {
    int idx = blockIdx.x * 256 + threadIdx.x;   // grid covers 4,194,304
    if (idx < 2097152) cat[idx] = mem[idx];
    else cat[idx] = h[idx - 2097152];
}

// generic fp32 GEMM: C[M,N] = A[M,K] @ B[K,N] (+bias) (+relu). M,N %64==0, K%16==0
template<int ACT>
__global__ __launch_bounds__(256) void gemm_kernel(const float* __restrict__ A,
    const float* __restrict__ B, const float* __restrict__ bias,
    float* __restrict__ C, int M, int N, int K) {
    __shared__ float As[16][65];
    __shared__ float Bs[16][64];
    int tid = threadIdx.x;
    int tx = tid & 15, ty = tid >> 4;
    int m0 = blockIdx.y * 64, n0 = blockIdx.x * 64;
    int arow = tid >> 2;            // 0..63
    int ak4  = (tid & 3) * 4;       // 0,4,8,12
    int bk   = tid >> 4;            // 0..15
    int bn4  = (tid & 15) * 4;      // 0..60
    const float* Aptr = A + (size_t)(m0 + arow) * K + ak4;
    const float* Bptr = B + (size_t)bk * N + n0 + bn4;
    float acc[4][4] = {};
    for (int k0 = 0; k0 < K; k0 += 16) {
        float4 av = *reinterpret_cast<const float4*>(Aptr + k0);
        float4 bv = *reinterpret_cast<const float4*>(Bptr + (size_t)k0 * N);
        As[ak4 + 0][arow] = av.x;
        As[ak4 + 1][arow] = av.y;
        As[ak4 + 2][arow] = av.z;
        As[ak4 + 3][arow] = av.w;
        *reinterpret_cast<float4*>(&Bs[bk][bn4]) = bv;
        __syncthreads();
        #pragma unroll
        for (int kk = 0; kk < 16; ++kk) {
            float a[4], b[4];
            #pragma unroll
            for (int u = 0; u < 4; ++u) { a[u] = As[kk][ty * 4 + u]; b[u] = Bs[kk][tx * 4 + u]; }
            #pragma unroll
            for (int u = 0; u < 4; ++u)
                #pragma unroll
                for (int v = 0; v < 4; ++v) acc[u][v] += a[u] * b[v];
        }
        __syncthreads();
    }
    #pragma unroll
    for (int u = 0; u < 4; ++u) {
        int m = m0 + ty * 4 + u;
        #pragma unroll
        for (int v = 0; v < 4; ++v) {
            int n = n0 + tx * 4 + v;
            float val = acc[u][v];
            if (bias) val += bias[n];
            if (ACT == 1) val = fmaxf(val, 0.0f);
            C[(size_t)m * N + n] = val;
        }
    }
}

// attention scores + mask + softmax -> prob[i][b][n][j]
__global__ __launch_bounds__(256) void attn_score_kernel(const float* __restrict__ wh,
    const float* __restrict__ rhk, const float* __restrict__ rwb,
    const float* __restrict__ rrb, float* __restrict__ prob) {
    int i = blockIdx.x, b = blockIdx.y, n = blockIdx.z;
    int tid = threadIdx.x;
    __shared__ float qw[64], qr[64];
    __shared__ float sc[512];
    __shared__ float red[256];
    const float* qrow = wh + ((size_t)(MLEN + i) * BSZ + b) * 3072 + n * DHEAD;
    if (tid < 64) {
        float qv = qrow[tid];
        qw[tid] = qv + rwb[n * DHEAD + tid];
        qr[tid] = qv + rrb[n * DHEAD + tid];
    }
    __syncthreads();
    float sv[2];
    for (int jj = 0; jj < 2; ++jj) {
        int j = tid + jj * 256;
        float s;
        if (j <= i + MLEN) {
            const float* krow = wh + ((size_t)j * BSZ + b) * 3072 + 1024 + n * DHEAD;
            int r = j + QLEN - 1 - i;
            const float* rrow = rhk + ((size_t)r * NHEAD + n) * DHEAD;
            float ac = 0.0f, bd = 0.0f;
            #pragma unroll 8
            for (int d = 0; d < DHEAD; ++d) {
                ac += qw[d] * krow[d];
                bd += qr[d] * rrow[d];
            }
            s = (ac + bd) * 0.125f;
        } else {
            s = -1e30f;
        }
        sv[jj] = s;
        sc[j] = s;
    }
    __syncthreads();
    // max reduce
    red[tid] = fmaxf(sv[0], sv[1]);
    __syncthreads();
    for (int st = 128; st > 0; st >>= 1) {
        if (tid < st) red[tid] = fmaxf(red[tid], red[tid + st]);
        __syncthreads();
    }
    float M = red[0];
    __syncthreads();
    float e0 = expf(sv[0] - M), e1 = expf(sv[1] - M);
    red[tid] = e0 + e1;
    __syncthreads();
    for (int st = 128; st > 0; st >>= 1) {
        if (tid < st) red[tid] += red[tid + st];
        __syncthreads();
    }
    float S = red[0];
    float* pr = prob + (((size_t)i * BSZ + b) * NHEAD + n) * KLEN;
    pr[tid] = e0 / S;
    pr[tid + 256] = e1 / S;
}

// vec[i][b][n*64+d] = sum_j prob[i,b,n,j] * v[j,b,n,d]
__global__ __launch_bounds__(64) void attn_v_kernel(const float* __restrict__ prob,
    const float* __restrict__ wh, float* __restrict__ vec) {
    int i = blockIdx.x, b = blockIdx.y, n = blockIdx.z;
    int d = threadIdx.x;
    const float* p = prob + (((size_t)i * BSZ + b) * NHEAD + n) * KLEN;
    const float* vb = wh + (size_t)b * 3072 + 2048 + n * DHEAD + d;
    float acc = 0.0f;
    #pragma unroll 4
    for (int j = 0; j < KLEN; ++j) {
        acc += p[j] * vb[(size_t)j * BSZ * 3072];
    }
    vec[((size_t)i * BSZ + b) * DMODEL + n * DHEAD + d] = acc;
}

// h = LN(x + h) * g + b   (in place on h)
__global__ __launch_bounds__(256) void ln_kernel(const float* __restrict__ x,
    float* __restrict__ h, const float* __restrict__ g, const float* __restrict__ bb) {
    int t = blockIdx.x, tid = threadIdx.x;
    __shared__ float rs[256], rq[256];
    float v[4];
    float s = 0.0f, sq = 0.0f;
    for (int u = 0; u < 4; ++u) {
        int d = tid + u * 256;
        float val = x[(size_t)t * DMODEL + d] + h[(size_t)t * DMODEL + d];
        v[u] = val; s += val; sq += val * val;
    }
    rs[tid] = s; rq[tid] = sq;
    __syncthreads();
    for (int st = 128; st > 0; st >>= 1) {
        if (tid < st) { rs[tid] += rs[tid + st]; rq[tid] += rq[tid + st]; }
        __syncthreads();
    }
    float mean = rs[0] * (1.0f / DMODEL);
    float var = rq[0] * (1.0f / DMODEL) - mean * mean;
    float r = rsqrtf(var + 1e-3f);
    for (int u = 0; u < 4; ++u) {
        int d = tid + u * 256;
        h[(size_t)t * DMODEL + d] = (v[u] - mean) * r * g[d] + bb[d];
    }
}

// logits tile GEMM + per-token (max,sumexp) partials.
// A = out_w (32000 x 1024) row-major, B = h^T (logical 1024 x 2048)
// block: (vtile=blockIdx.x of 500, ttile=blockIdx.y of 32), 64x64 tile
__global__ __launch_bounds__(256) void logits_lse_kernel(const float* __restrict__ W,
    const float* __restrict__ h, const float* __restrict__ ob,
    float* __restrict__ pmax, float* __restrict__ psum) {
    __shared__ float As[16][65];
    __shared__ float Bs[16][65];
    __shared__ float red2[16][64];
    __shared__ float cmax[64];
    int tid = threadIdx.x;
    int tx = tid & 15, ty = tid >> 4;
    int m0 = blockIdx.x * 64;   // vocab
    int t0 = blockIdx.y * 64;   // tokens
    int arow = tid >> 2;            // 0..63
    int ak4  = (tid & 3) * 4;
    const float* Aptr = W + (size_t)(m0 + arow) * DMODEL + ak4;
    const float* Bptr = h + (size_t)(t0 + arow) * DMODEL + ak4;
    float acc[4][4] = {};
    for (int k0 = 0; k0 < DMODEL; k0 += 16) {
        float4 av = *reinterpret_cast<const float4*>(Aptr + k0);
        float4 bv = *reinterpret_cast<const float4*>(Bptr + k0);
        As[ak4 + 0][arow] = av.x;
        As[ak4 + 1][arow] = av.y;
        As[ak4 + 2][arow] = av.z;
        As[ak4 + 3][arow] = av.w;
        Bs[ak4 + 0][arow] = bv.x;
        Bs[ak4 + 1][arow] = bv.y;
        Bs[ak4 + 2][arow] = bv.z;
        Bs[ak4 + 3][arow] = bv.w;
        __syncthreads();
        #pragma unroll
        for (int kk = 0; kk < 16; ++kk) {
            float a[4], b[4];
            #pragma unroll
            for (int u = 0; u < 4; ++u) { a[u] = As[kk][ty * 4 + u]; b[u] = Bs[kk][tx * 4 + u]; }
            #pragma unroll
            for (int u = 0; u < 4; ++u)
                #pragma unroll
                for (int v = 0; v < 4; ++v) acc[u][v] += a[u] * b[v];
        }
        __syncthreads();
    }
    // add bias per vocab row
    float lv[4][4];
    #pragma unroll
    for (int u = 0; u < 4; ++u) {
        float bias = ob[m0 + ty * 4 + u];
        #pragma unroll
        for (int v = 0; v < 4; ++v) lv[u][v] = acc[u][v] + bias;
    }
    // per-column (token) max over 64 vocab rows
    #pragma unroll
    for (int v = 0; v < 4; ++v) {
        float lm = lv[0][v];
        #pragma unroll
        for (int u = 1; u < 4; ++u) lm = fmaxf(lm, lv[u][v]);
        red2[ty][tx * 4 + v] = lm;
    }
    __syncthreads();
    if (tid < 64) {
        float m = red2[0][tid];
        #pragma unroll
        for (int r = 1; r < 16; ++r) m = fmaxf(m, red2[r][tid]);
        cmax[tid] = m;
    }
    __syncthreads();
    #pragma unroll
    for (int v = 0; v < 4; ++v) {
        float cm = cmax[tx * 4 + v];
        float ls = 0.0f;
        #pragma unroll
        for (int u = 0; u < 4; ++u) ls += expf(lv[u][v] - cm);
        red2[ty][tx * 4 + v] = ls;
    }
    __syncthreads();
    if (tid < 64) {
        float s = 0.0f;
        #pragma unroll
        for (int r = 1; r < 16; ++r) s += red2[r][tid];
        s += red2[0][tid];
        pmax[(size_t)(t0 + tid) * VTILES + blockIdx.x] = cmax[tid];
        psum[(size_t)(t0 + tid) * VTILES + blockIdx.x] = s;
    }
}

// target logit per token
__global__ __launch_bounds__(64) void tgt_kernel(const float* __restrict__ h,
    const float* __restrict__ W, const float* __restrict__ ob,
    const int* __restrict__ target, float* __restrict__ tgt) {
    int t = blockIdx.x;
    int lane = threadIdx.x;
    int row = target[t];
    const float* hp = h + (size_t)t * DMODEL;
    const float* wp = W + (size_t)row * DMODEL;
    float s = 0.0f;
    for (int d = lane; d < DMODEL; d += 64) s += hp[d] * wp[d];
    for (int o = 32; o > 0; o >>= 1) s += __shfl_down(s, o);
    if (lane == 0) tgt[t] = s + ob[row];
}

// combine partials -> lse[t]
__global__ __launch_bounds__(64) void lse_kernel(const float* __restrict__ pmax,
    const float* __restrict__ psum, float* __restrict__ lse) {
    int t = blockIdx.x;
    int lane = threadIdx.x;
    const float* pm = pmax + (size_t)t * VTILES;
    const float* ps = psum + (size_t)t * VTILES;
    float m = -1e30f;
    for (int c = lane; c < VTILES; c += 64) m = fmaxf(m, pm[c]);
    for (int o = 32; o > 0; o >>= 1) m = fmaxf(m, __shfl_xor(m, o));
    float s = 0.0f;
    for (int c = lane; c < VTILES; c += 64) s += ps[c] * expf(pm[c] - m);
    for (int o = 32; o > 0; o >>= 1) s += __shfl_xor(s, o);
    if (lane == 0) lse[t] = m + logf(s);
}

// loss = mean((lse - tgt) * mask)
__global__ __launch_bounds__(256) void loss_kernel(const float* __restrict__ lse,
    const float* __restrict__ tgt, const float* __restrict__ vm, float* __restrict__ out) {
    __shared__ float red[256];
    int tid = threadIdx.x;
    float s = 0.0f;
    for (int t = tid; t < NTOKENS_TOT; t += 256) s += (lse[t] - tgt[t]) * vm[t];
    red[tid] = s;
    __syncthreads();
    for (int st = 128; st > 0; st >>= 1) {
        if (tid < st) red[tid] += red[tid + st];
        __syncthreads();
    }
    if (tid == 0) out[0] = red[0] * (1.0f / NTOKENS_TOT);
}

// ---------------- launch ----------------
extern "C" void kernel_launch(void* const* d_in, const int* in_sizes, int n_in,
                              void* d_out, int out_size, void* d_ws, size_t ws_size,
                              hipStream_t stream) {
    const int*   dec_inp   = (const int*)  d_in[0];
    const int*   target    = (const int*)  d_in[1];
    const float* valid     = (const float*)d_in[2];
    const float* mems      = (const float*)d_in[3];
    const float* vocab_emb = (const float*)d_in[4];
    const float* out_w     = (const float*)d_in[5];
    const float* out_b     = (const float*)d_in[6];
    const float* qkv_w     = (const float*)d_in[7];
    const float* r_w       = (const float*)d_in[8];
    const float* o_w       = (const float*)d_in[9];
    const float* ln1_g     = (const float*)d_in[10];
    const float* ln1_b     = (const float*)d_in[11];
    const float* ff_w1     = (const float*)d_in[12];
    const float* ff_b1     = (const float*)d_in[13];
    const float* ff_w2     = (const float*)d_in[14];
    const float* ff_b2     = (const float*)d_in[15];
    const float* ln2_g     = (const float*)d_in[16];
    const float* ln2_b     = (const float*)d_in[17];
    const float* r_w_bias  = (const float*)d_in[18];
    const float* r_r_bias  = (const float*)d_in[19];

    float* ws = (float*)d_ws;
    float* h    = ws + O_H;
    float* cat  = ws + O_CAT;
    float* wh   = ws + O_WH;
    float* t1   = ws + O_T1;
    float* t2   = ws + O_T2;
    float* pos  = ws + O_POS;
    float* rhk  = ws + O_RHK;
    float* prob = ws + O_PROB;
    float* vec  = ws + O_VEC;
    float* pmax = ws + O_PMAX;
    float* psum = ws + O_PSUM;
    float* lse  = ws + O_LSE;
    float* tgt  = ws + O_TGT;

    embed_kernel<<<NTOKENS_TOT, 256, 0, stream>>>(dec_inp, vocab_emb, h);
    posemb_kernel<<<KLEN, 256, 0, stream>>>(pos);

    for (int l = 0; l < NLAYER; ++l) {
        const float* mem_l  = mems  + (size_t)l * MLEN * BSZ * DMODEL;
        const float* qkvw_l = qkv_w + (size_t)l * DMODEL * 3072;
        const float* rw_l   = r_w   + (size_t)l * DMODEL * DMODEL;
        const float* ow_l   = o_w   + (size_t)l * DMODEL * DMODEL;
        const float* ffw1_l = ff_w1 + (size_t)l * DMODEL * DINNER;
        const float* ffb1_l = ff_b1 + (size_t)l * DINNER;
        const float* ffw2_l = ff_w2 + (size_t)l * DINNER * DMODEL;
        const float* ffb2_l = ff_b2 + (size_t)l * DMODEL;

        cat_kernel<<<16384, 256, 0, stream>>>(mem_l, h, cat);
        // w_heads = cat(4096x1024) @ qkv_w[l](1024x3072)
        gemm_kernel<0><<<dim3(3072 / 64, 4096 / 64), 256, 0, stream>>>(
            cat, qkvw_l, nullptr, wh, 4096, 3072, 1024);
        // r_head_k = pos(512x1024) @ r_w[l](1024x1024)
        gemm_kernel<0><<<dim3(1024 / 64, 512 / 64), 256, 0, stream>>>(
            pos, rw_l, nullptr, rhk, 512, 1024, 1024);
        // scores + softmax
        attn_score_kernel<<<dim3(QLEN, BSZ, NHEAD), 256, 0, stream>>>(
            wh, rhk, r_w_bias, r_r_bias, prob);
        // prob @ v
        attn_v_kernel<<<dim3(QLEN, BSZ, NHEAD), 64, 0, stream>>>(prob, wh, vec);
        // attn out proj -> t1 (aliases wh; wh fully consumed by now)
        gemm_kernel<0><<<dim3(1024 / 64, 2048 / 64), 256, 0, stream>>>(
            vec, ow_l, nullptr, t1, 2048, 1024, 1024);
        // h = LN(t1 + h)
        ln_kernel<<<NTOKENS_TOT, 256, 0, stream>>>(t1, h, ln1_g + l * DMODEL, ln1_b + l * DMODEL);
        // ff1 = relu(h @ ff_w1 + b1) -> t1
        gemm_kernel<1><<<dim3(4096 / 64, 2048 / 64), 256, 0, stream>>>(
            h, ffw1_l, ffb1_l, t1, 2048, 4096, 1024);
        // ff2 = relu(t1 @ ff_w2 + b2) -> t2
        gemm_kernel<1><<<dim3(1024 / 64, 2048 / 64), 256, 0, stream>>>(
            t1, ffw2_l, ffb2_l, t2, 2048, 1024, 4096);
        // h = LN(t2 + h)
        ln_kernel<<<NTOKENS_TOT, 256, 0, stream>>>(t2, h, ln2_g + l * DMODEL, ln2_b + l * DMODEL);
    }

    // final: logits partial lse + target logit + combine + mean
    logits_lse_kernel<<<dim3(VTILES, NTOKENS_TOT / 64), 256, 0, stream>>>(
        out_w, h, out_b, pmax, psum);
    tgt_kernel<<<NTOKENS_TOT, 64, 0, stream>>>(h, out_w, out_b, target, tgt);
    lse_kernel<<<NTOKENS_TOT, 64, 0, stream>>>(pmax, psum, lse);
    loss_kernel<<<1, 256, 0, stream>>>(lse, tgt, valid, (float*)d_out);
}

// Round 2
// 2123.131 us; speedup vs baseline: 3.1859x; 3.1859x over previous
//
#include <hip/hip_runtime.h>
#include <hip/hip_bf16.h>
#include <math.h>

// ---------------- problem constants ----------------
#define QLEN 256
#define MLEN 256
#define KLEN 512
#define BSZ 8
#define DMODEL 1024
#define NHEAD 16
#define DHEAD 64
#define DINNER 4096
#define NTOKEN 32000
#define NLAYER 2
#define NTOK 2048          // QLEN*BSZ
#define VTILES 250         // 32000/128

typedef __attribute__((ext_vector_type(8))) short bf16x8;
typedef __attribute__((ext_vector_type(4))) float f32x4;

__device__ __forceinline__ float b2f(ushort u) { return __uint_as_float(((unsigned)u) << 16); }
__device__ __forceinline__ ushort f2b(float x) {
  unsigned u = __float_as_uint(x);
  return (ushort)((u + 0x7fffu + ((u >> 16) & 1u)) >> 16);
}

// ---------------- workspace layout (float offsets) ----------------
static const size_t O_H      = 0;                    // h fp32          2,097,152
static const size_t O_HBF    = 2097152;              // h bf16          1,048,576
static const size_t O_POSBF  = 3145728;              // pos bf16          262,144
static const size_t O_QKVT   = 3407872;              // 2x 3072x1024 bf 3,145,728
static const size_t O_RWT    = O_QKVT + 3145728;     // 2x 1024x1024 bf 1,048,576
static const size_t O_OWT    = O_RWT + 1048576;      // 2x 1024x1024 bf 1,048,576
static const size_t O_FFW1T  = O_OWT + 1048576;      // 2x 4096x1024 bf 4,194,304
static const size_t O_FFW2T  = O_FFW1T + 4194304;    // 2x 1024x4096 bf 4,194,304
static const size_t O_SCR    = O_FFW2T + 4194304;    // = 17,039,360
static const size_t O_CATBF  = O_SCR;                // 4096x1024 bf    2,097,152
static const size_t O_WHBF   = O_SCR + 2097152;      // 4096x3072 bf    6,291,456
static const size_t O_RHKBF  = O_SCR + 8388608;      // 512x1024 bf       262,144
static const size_t O_VECBF  = O_SCR + 8650752;      // 2048x1024 bf    1,048,576
static const size_t O_TATTN  = O_SCR + 9699328;      // 2048x1024 f32   2,097,152
static const size_t O_PROBBF = O_SCR + 11796480;     // 2048x16x512 bf  8,388,608
static const size_t O_T1BF   = O_PROBBF;             // alias (prob dead in FF phase)
static const size_t O_T2     = O_PROBBF + 4194304;   // 2048x1024 f32 (alias)
// logits phase (aliases layer scratch, all dead by then):
static const size_t O_OUTWBF = O_SCR;                // 32000x1024 bf  16,384,000
static const size_t O_PMAX   = O_SCR + 16384000;     // 2048*250          512,000
static const size_t O_PSUM   = O_PMAX + 512000;      //                   512,000
static const size_t O_LSE    = O_PSUM + 512000;      // 2048
static const size_t O_TGT    = O_LSE + 2048;         // 2048
// total = 37,224,448 floats = 148.9 MB

// ---------------- small kernels ----------------

__global__ __launch_bounds__(256) void embed_kernel(const int* __restrict__ dec,
    const float* __restrict__ emb, float* __restrict__ h) {
    int t = blockIdx.x;
    int tok = dec[t];
    const float* src = emb + (size_t)tok * DMODEL;
    float* dst = h + (size_t)t * DMODEL;
    for (int u = 0; u < 4; ++u) {
        int d = threadIdx.x + u * 256;
        dst[d] = src[d] * 32.0f;
    }
}

__global__ __launch_bounds__(256) void posemb_kernel(ushort* __restrict__ pe) {
    int r = blockIdx.x;
    float pos = (float)(KLEN - 1 - r);
    for (int u = 0; u < 2; ++u) {
        int dp = threadIdx.x + u * 256;  // 0..511
        float inv = expf(-(float)dp * (9.210340371976184f / 512.0f));
        float ang = pos * inv;
        pe[(size_t)r * DMODEL + dp]       = f2b(sinf(ang));
        pe[(size_t)r * DMODEL + 512 + dp] = f2b(cosf(ang));
    }
}

// cat_bf = [mems_l ; h] converted to bf16; processed in float4 units (1,048,576 total)
__global__ __launch_bounds__(256) void cat_bf16_kernel(const float* __restrict__ mem,
    const float* __restrict__ h, ushort* __restrict__ out) {
    size_t i = (size_t)blockIdx.x * 256 + threadIdx.x;
    float4 v;
    if (i < 524288) v = ((const float4*)mem)[i];
    else            v = ((const float4*)h)[i - 524288];
    ushort4 o;
    o.x = f2b(v.x); o.y = f2b(v.y); o.z = f2b(v.z); o.w = f2b(v.w);
    ((ushort4*)out)[i] = o;
}

// W[K][N] fp32 -> Wt[N][K] bf16
__global__ __launch_bounds__(256) void transpose_bf16_kernel(const float* __restrict__ W,
    ushort* __restrict__ Wt, int K, int N) {
    __shared__ float tile[32][33];
    int tx = threadIdx.x & 31, ty = threadIdx.x >> 5;   // 32 x 8
    int n0 = blockIdx.x * 32, k0 = blockIdx.y * 32;
    for (int u = 0; u < 4; ++u)
        tile[ty + u * 8][tx] = W[(size_t)(k0 + ty + u * 8) * N + n0 + tx];
    __syncthreads();
    for (int u = 0; u < 4; ++u)
        Wt[(size_t)(n0 + ty + u * 8) * K + k0 + tx] = f2b(tile[tx][ty + u * 8]);
}

// straight fp32 -> bf16 (float4 granularity)
__global__ __launch_bounds__(256) void convert_bf16_kernel(const float* __restrict__ W,
    ushort* __restrict__ Wb) {
    size_t i = (size_t)blockIdx.x * 256 + threadIdx.x;
    float4 v = ((const float4*)W)[i];
    ushort4 o;
    o.x = f2b(v.x); o.y = f2b(v.y); o.z = f2b(v.z); o.w = f2b(v.w);
    ((ushort4*)Wb)[i] = o;
}

// ---------------- bf16 MFMA GEMM ----------------
// C[M,N] = A[M,K] * Bt[N,K]^T  (both bf16 row-major with K contiguous)
// 128x128 tile, BK=32, 4 waves in 2x2, each wave 64x64 (4x4 fragments 16x16x32)
// LDS rows padded to 40 shorts (80B) -> 2-way bank aliasing (free).
template<int OUTBF, int ACT>
__global__ __launch_bounds__(256) void gemm_bf16_kernel(
    const ushort* __restrict__ A, const ushort* __restrict__ Bt,
    const float* __restrict__ bias, void* __restrict__ Cout,
    int M, int N, int K) {
    __shared__ ushort As[128 * 40];
    __shared__ ushort Bs[128 * 40];
    const int tid = threadIdx.x;
    const int wave = tid >> 6, lane = tid & 63;
    const int m0 = blockIdx.y * 128, n0 = blockIdx.x * 128;
    const int wr = wave >> 1, wc = wave & 1;
    const int srow = tid >> 1, shalf = tid & 1;
    const ushort* Ap = A + (size_t)(m0 + srow) * K + shalf * 16;
    const ushort* Bp = Bt + (size_t)(n0 + srow) * K + shalf * 16;
    ushort* Asw = &As[srow * 40 + shalf * 16];
    ushort* Bsw = &Bs[srow * 40 + shalf * 16];
    const int fr = lane & 15, kq = lane >> 4;
    const ushort* Ard = &As[(wr * 64 + fr) * 40 + kq * 8];
    const ushort* Brd = &Bs[(wc * 64 + fr) * 40 + kq * 8];
    f32x4 acc[4][4] = {};
    for (int k0 = 0; k0 < K; k0 += 32) {
        float4 a0 = *(const float4*)(Ap + k0);
        float4 a1 = *(const float4*)(Ap + k0 + 8);
        float4 b0 = *(const float4*)(Bp + k0);
        float4 b1 = *(const float4*)(Bp + k0 + 8);
        *(float4*)(Asw)     = a0; *(float4*)(Asw + 8) = a1;
        *(float4*)(Bsw)     = b0; *(float4*)(Bsw + 8) = b1;
        __syncthreads();
        bf16x8 af[4], bfr[4];
        #pragma unroll
        for (int i = 0; i < 4; ++i) af[i]  = *(const bf16x8*)(Ard + i * 16 * 40);
        #pragma unroll
        for (int i = 0; i < 4; ++i) bfr[i] = *(const bf16x8*)(Brd + i * 16 * 40);
        #pragma unroll
        for (int mi = 0; mi < 4; ++mi)
            #pragma unroll
            for (int ni = 0; ni < 4; ++ni)
                acc[mi][ni] = __builtin_amdgcn_mfma_f32_16x16x32_bf16(
                    af[mi], bfr[ni], acc[mi][ni], 0, 0, 0);
        __syncthreads();
    }
    float* Cf  = (float*)Cout;
    ushort* Cb = (ushort*)Cout;
    #pragma unroll
    for (int ni = 0; ni < 4; ++ni) {
        int cg = n0 + wc * 64 + ni * 16 + fr;
        float bv = bias ? bias[cg] : 0.0f;
        #pragma unroll
        for (int mi = 0; mi < 4; ++mi) {
            int rg = m0 + wr * 64 + mi * 16 + kq * 4;   // C/D: row=(lane>>4)*4+reg
            #pragma unroll
            for (int r = 0; r < 4; ++r) {
                float v = acc[mi][ni][r] + bv;
                if (ACT) v = fmaxf(v, 0.0f);
                if (OUTBF) Cb[(size_t)(rg + r) * N + cg] = f2b(v);
                else       Cf[(size_t)(rg + r) * N + cg] = v;
            }
        }
    }
}

// logits GEMM + fused per-token (max, sumexp) over the 128-vocab tile.
// A = out_w bf16 [32000][1024], Bt = h bf16 [2048][1024]
__global__ __launch_bounds__(256) void logits_lse_kernel(
    const ushort* __restrict__ A, const ushort* __restrict__ Bt,
    const float* __restrict__ ob, float* __restrict__ pmax, float* __restrict__ psum) {
    __shared__ ushort As[128 * 40];
    __shared__ ushort Bs[128 * 40];
    __shared__ float redm[2][128], reds[2][128];
    const int tid = threadIdx.x;
    const int wave = tid >> 6, lane = tid & 63;
    const int m0 = blockIdx.x * 128;   // vocab
    const int t0 = blockIdx.y * 128;   // tokens
    const int wr = wave >> 1, wc = wave & 1;
    const int srow = tid >> 1, shalf = tid & 1;
    const ushort* Ap = A + (size_t)(m0 + srow) * DMODEL + shalf * 16;
    const ushort* Bp = Bt + (size_t)(t0 + srow) * DMODEL + shalf * 16;
    ushort* Asw = &As[srow * 40 + shalf * 16];
    ushort* Bsw = &Bs[srow * 40 + shalf * 16];
    const int fr = lane & 15, kq = lane >> 4;
    const ushort* Ard = &As[(wr * 64 + fr) * 40 + kq * 8];
    const ushort* Brd = &Bs[(wc * 64 + fr) * 40 + kq * 8];
    f32x4 acc[4][4] = {};
    for (int k0 = 0; k0 < DMODEL; k0 += 32) {
        float4 a0 = *(const float4*)(Ap + k0);
        float4 a1 = *(const float4*)(Ap + k0 + 8);
        float4 b0 = *(const float4*)(Bp + k0);
        float4 b1 = *(const float4*)(Bp + k0 + 8);
        *(float4*)(Asw)     = a0; *(float4*)(Asw + 8) = a1;
        *(float4*)(Bsw)     = b0; *(float4*)(Bsw + 8) = b1;
        __syncthreads();
        bf16x8 af[4], bfr[4];
        #pragma unroll
        for (int i = 0; i < 4; ++i) af[i]  = *(const bf16x8*)(Ard + i * 16 * 40);
        #pragma unroll
        for (int i = 0; i < 4; ++i) bfr[i] = *(const bf16x8*)(Brd + i * 16 * 40);
        #pragma unroll
        for (int mi = 0; mi < 4; ++mi)
            #pragma unroll
            for (int ni = 0; ni < 4; ++ni)
                acc[mi][ni] = __builtin_amdgcn_mfma_f32_16x16x32_bf16(
                    af[mi], bfr[ni], acc[mi][ni], 0, 0, 0);
        __syncthreads();
    }
    // epilogue: per token-column, max & sum(exp) over this 128-row vocab tile
    #pragma unroll
    for (int ni = 0; ni < 4; ++ni) {
        float vals[16];
        float vmax = -1e30f;
        #pragma unroll
        for (int mi = 0; mi < 4; ++mi) {
            int rg = m0 + wr * 64 + mi * 16 + kq * 4;
            float4 ob4 = *(const float4*)&ob[rg];
            float o4[4] = {ob4.x, ob4.y, ob4.z, ob4.w};
            #pragma unroll
            for (int r = 0; r < 4; ++r) {
                float v = acc[mi][ni][r] + o4[r];
                vals[mi * 4 + r] = v;
                vmax = fmaxf(vmax, v);
            }
        }
        vmax = fmaxf(vmax, __shfl_xor(vmax, 16));
        vmax = fmaxf(vmax, __shfl_xor(vmax, 32));
        float s = 0.0f;
        #pragma unroll
        for (int q = 0; q < 16; ++q) s += __expf(vals[q] - vmax);
        s += __shfl_xor(s, 16);
        s += __shfl_xor(s, 32);
        if (kq == 0) {
            redm[wr][wc * 64 + ni * 16 + fr] = vmax;
            reds[wr][wc * 64 + ni * 16 + fr] = s;
        }
    }
    __syncthreads();
    if (tid < 128) {
        float ma = redm[0][tid], mb = redm[1][tid];
        float m = fmaxf(ma, mb);
        float s = reds[0][tid] * __expf(ma - m) + reds[1][tid] * __expf(mb - m);
        pmax[(size_t)(t0 + tid) * VTILES + blockIdx.x] = m;
        psum[(size_t)(t0 + tid) * VTILES + blockIdx.x] = s;
    }
}

// ---------------- attention (fp32 math over bf16 data) ----------------

__global__ __launch_bounds__(256) void attn_score_kernel(const ushort* __restrict__ wh,
    const ushort* __restrict__ rhk, const float* __restrict__ rwb,
    const float* __restrict__ rrb, ushort* __restrict__ prob) {
    int i = blockIdx.x, b = blockIdx.y, n = blockIdx.z;
    int tid = threadIdx.x;
    __shared__ float qw[64], qr[64];
    __shared__ float red[256];
    const ushort* qrow = wh + ((size_t)(MLEN + i) * BSZ + b) * 3072 + n * DHEAD;
    if (tid < 64) {
        float qv = b2f(qrow[tid]);
        qw[tid] = qv + rwb[n * DHEAD + tid];
        qr[tid] = qv + rrb[n * DHEAD + tid];
    }
    __syncthreads();
    float sv[2];
    for (int jj = 0; jj < 2; ++jj) {
        int j = tid + jj * 256;
        float s;
        if (j <= i + MLEN) {
            const ushort4* kp = (const ushort4*)(wh + ((size_t)j * BSZ + b) * 3072 + 1024 + n * DHEAD);
            int r = j + QLEN - 1 - i;
            const ushort4* rp = (const ushort4*)(rhk + (size_t)r * DMODEL + n * DHEAD);
            float ac = 0.0f, bd = 0.0f;
            #pragma unroll 4
            for (int dq = 0; dq < 16; ++dq) {
                ushort4 kv = kp[dq]; ushort4 rv = rp[dq];
                ac += qw[dq*4+0]*b2f(kv.x) + qw[dq*4+1]*b2f(kv.y)
                    + qw[dq*4+2]*b2f(kv.z) + qw[dq*4+3]*b2f(kv.w);
                bd += qr[dq*4+0]*b2f(rv.x) + qr[dq*4+1]*b2f(rv.y)
                    + qr[dq*4+2]*b2f(rv.z) + qr[dq*4+3]*b2f(rv.w);
            }
            s = (ac + bd) * 0.125f;
        } else {
            s = -1e30f;
        }
        sv[jj] = s;
    }
    red[tid] = fmaxf(sv[0], sv[1]);
    __syncthreads();
    for (int st = 128; st > 0; st >>= 1) {
        if (tid < st) red[tid] = fmaxf(red[tid], red[tid + st]);
        __syncthreads();
    }
    float M = red[0];
    __syncthreads();
    float e0 = __expf(sv[0] - M), e1 = __expf(sv[1] - M);
    red[tid] = e0 + e1;
    __syncthreads();
    for (int st = 128; st > 0; st >>= 1) {
        if (tid < st) red[tid] += red[tid + st];
        __syncthreads();
    }
    float inv = 1.0f / red[0];
    ushort* pr = prob + (((size_t)i * BSZ + b) * NHEAD + n) * KLEN;
    pr[tid]       = f2b(e0 * inv);
    pr[tid + 256] = f2b(e1 * inv);
}

__global__ __launch_bounds__(64) void attn_v_kernel(const ushort* __restrict__ prob,
    const ushort* __restrict__ wh, ushort* __restrict__ vec) {
    int i = blockIdx.x, b = blockIdx.y, n = blockIdx.z;
    int d = threadIdx.x;
    const ushort* p = prob + (((size_t)i * BSZ + b) * NHEAD + n) * KLEN;
    const ushort* vb = wh + (size_t)b * 3072 + 2048 + n * DHEAD + d;
    float acc = 0.0f;
    #pragma unroll 4
    for (int j = 0; j < KLEN; ++j) {
        acc += b2f(p[j]) * b2f(vb[(size_t)j * BSZ * 3072]);
    }
    vec[((size_t)i * BSZ + b) * DMODEL + n * DHEAD + d] = f2b(acc);
}

// h = LN(x + h)*g + b, writes fp32 h and bf16 copy
__global__ __launch_bounds__(256) void ln_kernel(const float* __restrict__ x,
    float* __restrict__ h, const float* __restrict__ g, const float* __restrict__ bb,
    ushort* __restrict__ hb) {
    int t = blockIdx.x, tid = threadIdx.x;
    __shared__ float rs[256], rq[256];
    float v[4];
    float s = 0.0f, sq = 0.0f;
    for (int u = 0; u < 4; ++u) {
        int d = tid + u * 256;
        float val = x[(size_t)t * DMODEL + d] + h[(size_t)t * DMODEL + d];
        v[u] = val; s += val; sq += val * val;
    }
    rs[tid] = s; rq[tid] = sq;
    __syncthreads();
    for (int st = 128; st > 0; st >>= 1) {
        if (tid < st) { rs[tid] += rs[tid + st]; rq[tid] += rq[tid + st]; }
        __syncthreads();
    }
    float mean = rs[0] * (1.0f / DMODEL);
    float var = rq[0] * (1.0f / DMODEL) - mean * mean;
    float r = rsqrtf(var + 1e-3f);
    for (int u = 0; u < 4; ++u) {
        int d = tid + u * 256;
        float o = (v[u] - mean) * r * g[d] + bb[d];
        h[(size_t)t * DMODEL + d] = o;
        hb[(size_t)t * DMODEL + d] = f2b(o);
    }
}

// ---------------- final loss pieces ----------------

__global__ __launch_bounds__(64) void tgt_kernel(const float* __restrict__ h,
    const float* __restrict__ W, const float* __restrict__ ob,
    const int* __restrict__ target, float* __restrict__ tgt) {
    int t = blockIdx.x;
    int lane = threadIdx.x;
    int row = target[t];
    const float* hp = h + (size_t)t * DMODEL;
    const float* wp = W + (size_t)row * DMODEL;
    float s = 0.0f;
    for (int d = lane; d < DMODEL; d += 64) s += hp[d] * wp[d];
    for (int o = 32; o > 0; o >>= 1) s += __shfl_down(s, o);
    if (lane == 0) tgt[t] = s + ob[row];
}

__global__ __launch_bounds__(64) void lse_kernel(const float* __restrict__ pmax,
    const float* __restrict__ psum, float* __restrict__ lse) {
    int t = blockIdx.x;
    int lane = threadIdx.x;
    const float* pm = pmax + (size_t)t * VTILES;
    const float* ps = psum + (size_t)t * VTILES;
    float m = -1e30f;
    for (int c = lane; c < VTILES; c += 64) m = fmaxf(m, pm[c]);
    for (int o = 32; o > 0; o >>= 1) m = fmaxf(m, __shfl_xor(m, o));
    float s = 0.0f;
    for (int c = lane; c < VTILES; c += 64) s += ps[c] * expf(pm[c] - m);
    for (int o = 32; o > 0; o >>= 1) s += __shfl_xor(s, o);
    if (lane == 0) lse[t] = m + logf(s);
}

__global__ __launch_bounds__(256) void loss_kernel(const float* __restrict__ lse,
    const float* __restrict__ tgt, const float* __restrict__ vm, float* __restrict__ out) {
    __shared__ float red[256];
    int tid = threadIdx.x;
    float s = 0.0f;
    for (int t = tid; t < NTOK; t += 256) s += (lse[t] - tgt[t]) * vm[t];
    red[tid] = s;
    __syncthreads();
    for (int st = 128; st > 0; st >>= 1) {
        if (tid < st) red[tid] += red[tid + st];
        __syncthreads();
    }
    if (tid == 0) out[0] = red[0] * (1.0f / NTOK);
}

// ---------------- launch ----------------
extern "C" void kernel_launch(void* const* d_in, const int* in_sizes, int n_in,
                              void* d_out, int out_size, void* d_ws, size_t ws_size,
                              hipStream_t stream) {
    const int*   dec_inp   = (const int*)  d_in[0];
    const int*   target    = (const int*)  d_in[1];
    const float* valid     = (const float*)d_in[2];
    const float* mems      = (const float*)d_in[3];
    const float* vocab_emb = (const float*)d_in[4];
    const float* out_w     = (const float*)d_in[5];
    const float* out_b     = (const float*)d_in[6];
    const float* qkv_w     = (const float*)d_in[7];
    const float* r_w       = (const float*)d_in[8];
    const float* o_w       = (const float*)d_in[9];
    const float* ln1_g     = (const float*)d_in[10];
    const float* ln1_b     = (const float*)d_in[11];
    const float* ff_w1     = (const float*)d_in[12];
    const float* ff_b1     = (const float*)d_in[13];
    const float* ff_w2     = (const float*)d_in[14];
    const float* ff_b2     = (const float*)d_in[15];
    const float* ln2_g     = (const float*)d_in[16];
    const float* ln2_b     = (const float*)d_in[17];
    const float* r_w_bias  = (const float*)d_in[18];
    const float* r_r_bias  = (const float*)d_in[19];

    float* ws = (float*)d_ws;
    float*  h      = ws + O_H;
    ushort* hbf    = (ushort*)(ws + O_HBF);
    ushort* posbf  = (ushort*)(ws + O_POSBF);
    ushort* qkvt   = (ushort*)(ws + O_QKVT);
    ushort* rwt    = (ushort*)(ws + O_RWT);
    ushort* owt    = (ushort*)(ws + O_OWT);
    ushort* ffw1t  = (ushort*)(ws + O_FFW1T);
    ushort* ffw2t  = (ushort*)(ws + O_FFW2T);
    ushort* catbf  = (ushort*)(ws + O_CATBF);
    ushort* whbf   = (ushort*)(ws + O_WHBF);
    ushort* rhkbf  = (ushort*)(ws + O_RHKBF);
    ushort* vecbf  = (ushort*)(ws + O_VECBF);
    float*  tattn  = ws + O_TATTN;
    ushort* probbf = (ushort*)(ws + O_PROBBF);
    ushort* t1bf   = (ushort*)(ws + O_T1BF);
    float*  t2     = ws + O_T2;
    ushort* outwbf = (ushort*)(ws + O_OUTWBF);
    float*  pmax   = ws + O_PMAX;
    float*  psum   = ws + O_PSUM;
    float*  lse    = ws + O_LSE;
    float*  tgt    = ws + O_TGT;

    // ---- weight prep (transpose + bf16) ----
    for (int l = 0; l < NLAYER; ++l) {
        transpose_bf16_kernel<<<dim3(96, 32), 256, 0, stream>>>(
            qkv_w + (size_t)l * DMODEL * 3072, qkvt + (size_t)l * 3072 * DMODEL, DMODEL, 3072);
        transpose_bf16_kernel<<<dim3(32, 32), 256, 0, stream>>>(
            r_w + (size_t)l * DMODEL * DMODEL, rwt + (size_t)l * DMODEL * DMODEL, DMODEL, DMODEL);
        transpose_bf16_kernel<<<dim3(32, 32), 256, 0, stream>>>(
            o_w + (size_t)l * DMODEL * DMODEL, owt + (size_t)l * DMODEL * DMODEL, DMODEL, DMODEL);
        transpose_bf16_kernel<<<dim3(128, 32), 256, 0, stream>>>(
            ff_w1 + (size_t)l * DMODEL * DINNER, ffw1t + (size_t)l * DINNER * DMODEL, DMODEL, DINNER);
        transpose_bf16_kernel<<<dim3(32, 128), 256, 0, stream>>>(
            ff_w2 + (size_t)l * DINNER * DMODEL, ffw2t + (size_t)l * DMODEL * DINNER, DINNER, DMODEL);
    }
    embed_kernel<<<NTOK, 256, 0, stream>>>(dec_inp, vocab_emb, h);
    posemb_kernel<<<KLEN, 256, 0, stream>>>(posbf);

    for (int l = 0; l < NLAYER; ++l) {
        const float* mem_l = mems + (size_t)l * MLEN * BSZ * DMODEL;
        cat_bf16_kernel<<<4096, 256, 0, stream>>>(mem_l, h, catbf);
        // wh = cat @ qkv_w  (4096 x 3072, K=1024) -> bf16
        gemm_bf16_kernel<1, 0><<<dim3(24, 32), 256, 0, stream>>>(
            catbf, qkvt + (size_t)l * 3072 * DMODEL, nullptr, whbf, 4096, 3072, DMODEL);
        // r_head_k = pos @ r_w  (512 x 1024) -> bf16
        gemm_bf16_kernel<1, 0><<<dim3(8, 4), 256, 0, stream>>>(
            posbf, rwt + (size_t)l * DMODEL * DMODEL, nullptr, rhkbf, KLEN, DMODEL, DMODEL);
        attn_score_kernel<<<dim3(QLEN, BSZ, NHEAD), 256, 0, stream>>>(
            whbf, rhkbf, r_w_bias, r_r_bias, probbf);
        attn_v_kernel<<<dim3(QLEN, BSZ, NHEAD), 64, 0, stream>>>(probbf, whbf, vecbf);
        // attn out proj (2048 x 1024, K=1024) -> f32
        gemm_bf16_kernel<0, 0><<<dim3(8, 16), 256, 0, stream>>>(
            vecbf, owt + (size_t)l * DMODEL * DMODEL, nullptr, tattn, NTOK, DMODEL, DMODEL);
        ln_kernel<<<NTOK, 256, 0, stream>>>(tattn, h, ln1_g + l * DMODEL, ln1_b + l * DMODEL, hbf);
        // ff1 = relu(h @ ff_w1 + b1) (2048 x 4096, K=1024) -> bf16
        gemm_bf16_kernel<1, 1><<<dim3(32, 16), 256, 0, stream>>>(
            hbf, ffw1t + (size_t)l * DINNER * DMODEL, ff_b1 + (size_t)l * DINNER, t1bf, NTOK, DINNER, DMODEL);
        // ff2 = relu(t1 @ ff_w2 + b2) (2048 x 1024, K=4096) -> f32
        gemm_bf16_kernel<0, 1><<<dim3(8, 16), 256, 0, stream>>>(
            t1bf, ffw2t + (size_t)l * DMODEL * DINNER, ff_b2 + (size_t)l * DMODEL, t2, NTOK, DMODEL, DINNER);
        ln_kernel<<<NTOK, 256, 0, stream>>>(t2, h, ln2_g + l * DMODEL, ln2_b + l * DMODEL, hbf);
    }

    // ---- final: logits LSE + target + combine + mean ----
    convert_bf16_kernel<<<32000, 256, 0, stream>>>(out_w, outwbf);  // 32,768,000/4 elems
    logits_lse_kernel<<<dim3(VTILES, NTOK / 128), 256, 0, stream>>>(
        outwbf, hbf, out_b, pmax, psum);
    tgt_kernel<<<NTOK, 64, 0, stream>>>(h, out_w, out_b, target, tgt);
    lse_kernel<<<NTOK, 64, 0, stream>>>(pmax, psum, lse);
    loss_kernel<<<1, 256, 0, stream>>>(lse, tgt, valid, (float*)d_out);
}

// Round 3
// 956.931 us; speedup vs baseline: 7.0685x; 2.2187x over previous
//
#include <hip/hip_runtime.h>
#include <hip/hip_bf16.h>
#include <math.h>

// ---------------- problem constants ----------------
#define QLEN 256
#define MLEN 256
#define KLEN 512
#define BSZ 8
#define DMODEL 1024
#define NHEAD 16
#define DHEAD 64
#define DINNER 4096
#define NTOKEN 32000
#define NLAYER 2
#define NTOK 2048          // QLEN*BSZ
#define VTILES 250         // 32000/128

typedef __attribute__((ext_vector_type(8))) short bf16x8;
typedef __attribute__((ext_vector_type(4))) float f32x4;

__device__ __forceinline__ float b2f(ushort u) { return __uint_as_float(((unsigned)u) << 16); }
__device__ __forceinline__ ushort f2b(float x) {
  unsigned u = __float_as_uint(x);
  return (ushort)((u + 0x7fffu + ((u >> 16) & 1u)) >> 16);
}

// ---------------- workspace layout (float offsets) ----------------
static const size_t O_H      = 0;                    // h fp32          2,097,152
static const size_t O_HBF    = 2097152;              // h bf16          1,048,576
static const size_t O_POSBF  = 3145728;              // pos bf16          262,144
static const size_t O_QKVT   = 3407872;              // 2x 3072x1024 bf 3,145,728
static const size_t O_RWT    = O_QKVT + 3145728;     // 2x 1024x1024 bf 1,048,576
static const size_t O_OWT    = O_RWT + 1048576;      // 2x 1024x1024 bf 1,048,576
static const size_t O_FFW1T  = O_OWT + 1048576;      // 2x 4096x1024 bf 4,194,304
static const size_t O_FFW2T  = O_FFW1T + 4194304;    // 2x 1024x4096 bf 4,194,304
static const size_t O_SCR    = O_FFW2T + 4194304;    // = 17,039,360
static const size_t O_CATBF  = O_SCR;                // 4096x1024 bf    2,097,152
// Q/K/V region (was whbf):
static const size_t O_QW     = O_SCR + 2097152;      // 8*16*256*64 bf  1,048,576
static const size_t O_QR     = O_QW + 1048576;       //                 1,048,576
static const size_t O_KG     = O_QR + 1048576;       // 8*16*512*64 bf  2,097,152
static const size_t O_VG     = O_KG + 2097152;       //                 2,097,152
static const size_t O_RHKT   = O_SCR + 8388608;      // 16*512*64 bf      262,144
static const size_t O_VECBF  = O_SCR + 8650752;      // 2048x1024 bf    1,048,576
static const size_t O_TATTN  = O_SCR + 9699328;      // 2048x1024 f32   2,097,152
static const size_t O_BDS    = O_SCR + 11796480;     // 128*256*512 bf  8,388,608
static const size_t O_T1BF   = O_BDS;                // alias (BD dead in FF phase)
static const size_t O_T2     = O_BDS + 4194304;      // 2048x1024 f32 (alias)
// logits phase (aliases layer scratch, all dead by then):
static const size_t O_OUTWBF = O_SCR;                // 32000x1024 bf  16,384,000
static const size_t O_PMAX   = O_SCR + 16384000;     // 2048*250          512,000
static const size_t O_PSUM   = O_PMAX + 512000;      //                   512,000
static const size_t O_LSE    = O_PSUM + 512000;      // 2048
static const size_t O_TGT    = O_LSE + 2048;         // 2048

// ---------------- small kernels ----------------

__global__ __launch_bounds__(256) void embed_kernel(const int* __restrict__ dec,
    const float* __restrict__ emb, float* __restrict__ h) {
    int t = blockIdx.x;
    int tok = dec[t];
    const float* src = emb + (size_t)tok * DMODEL;
    float* dst = h + (size_t)t * DMODEL;
    for (int u = 0; u < 4; ++u) {
        int d = threadIdx.x + u * 256;
        dst[d] = src[d] * 32.0f;
    }
}

__global__ __launch_bounds__(256) void posemb_kernel(ushort* __restrict__ pe) {
    int r = blockIdx.x;
    float pos = (float)(KLEN - 1 - r);
    for (int u = 0; u < 2; ++u) {
        int dp = threadIdx.x + u * 256;  // 0..511
        float inv = expf(-(float)dp * (9.210340371976184f / 512.0f));
        float ang = pos * inv;
        pe[(size_t)r * DMODEL + dp]       = f2b(sinf(ang));
        pe[(size_t)r * DMODEL + 512 + dp] = f2b(cosf(ang));
    }
}

__global__ __launch_bounds__(256) void cat_bf16_kernel(const float* __restrict__ mem,
    const float* __restrict__ h, ushort* __restrict__ out) {
    size_t i = (size_t)blockIdx.x * 256 + threadIdx.x;
    float4 v;
    if (i < 524288) v = ((const float4*)mem)[i];
    else            v = ((const float4*)h)[i - 524288];
    ushort4 o;
    o.x = f2b(v.x); o.y = f2b(v.y); o.z = f2b(v.z); o.w = f2b(v.w);
    ((ushort4*)out)[i] = o;
}

// W[K][N] fp32 -> Wt[N][K] bf16
__global__ __launch_bounds__(256) void transpose_bf16_kernel(const float* __restrict__ W,
    ushort* __restrict__ Wt, int K, int N) {
    __shared__ float tile[32][33];
    int tx = threadIdx.x & 31, ty = threadIdx.x >> 5;   // 32 x 8
    int n0 = blockIdx.x * 32, k0 = blockIdx.y * 32;
    for (int u = 0; u < 4; ++u)
        tile[ty + u * 8][tx] = W[(size_t)(k0 + ty + u * 8) * N + n0 + tx];
    __syncthreads();
    for (int u = 0; u < 4; ++u)
        Wt[(size_t)(n0 + ty + u * 8) * K + k0 + tx] = f2b(tile[tx][ty + u * 8]);
}

__global__ __launch_bounds__(256) void convert_bf16_kernel(const float* __restrict__ W,
    ushort* __restrict__ Wb) {
    size_t i = (size_t)blockIdx.x * 256 + threadIdx.x;
    float4 v = ((const float4*)W)[i];
    ushort4 o;
    o.x = f2b(v.x); o.y = f2b(v.y); o.z = f2b(v.z); o.w = f2b(v.w);
    ((ushort4*)Wb)[i] = o;
}

// ---------------- GEMM main-loop macro (128x128 tile, BK=32) ----------------
// defines: acc[4][4] accumulated; uses As/Bs LDS; needs A,Bt,K,m0,n0 set up.
#define GEMM_BODY(APTR, BPTR, KDIM)                                            \
    const int tid = threadIdx.x;                                               \
    const int wave = tid >> 6, lane = tid & 63;                                \
    const int wr = wave >> 1, wc = wave & 1;                                   \
    const int srow = tid >> 1, shalf = tid & 1;                                \
    const ushort* Ap = (APTR) + (size_t)(m0 + srow) * (KDIM) + shalf * 16;     \
    const ushort* Bp = (BPTR) + (size_t)(n0 + srow) * (KDIM) + shalf * 16;     \
    ushort* Asw = &As[srow * 40 + shalf * 16];                                 \
    ushort* Bsw = &Bs[srow * 40 + shalf * 16];                                 \
    const int fr = lane & 15, kq = lane >> 4;                                  \
    const ushort* Ard = &As[(wr * 64 + fr) * 40 + kq * 8];                     \
    const ushort* Brd = &Bs[(wc * 64 + fr) * 40 + kq * 8];                     \
    f32x4 acc[4][4] = {};                                                      \
    for (int k0 = 0; k0 < (KDIM); k0 += 32) {                                  \
        float4 a0 = *(const float4*)(Ap + k0);                                 \
        float4 a1 = *(const float4*)(Ap + k0 + 8);                             \
        float4 b0 = *(const float4*)(Bp + k0);                                 \
        float4 b1 = *(const float4*)(Bp + k0 + 8);                             \
        *(float4*)(Asw)     = a0; *(float4*)(Asw + 8) = a1;                    \
        *(float4*)(Bsw)     = b0; *(float4*)(Bsw + 8) = b1;                    \
        __syncthreads();                                                       \
        bf16x8 af[4], bfr[4];                                                  \
        _Pragma("unroll")                                                      \
        for (int i = 0; i < 4; ++i) af[i]  = *(const bf16x8*)(Ard + i * 16 * 40); \
        _Pragma("unroll")                                                      \
        for (int i = 0; i < 4; ++i) bfr[i] = *(const bf16x8*)(Brd + i * 16 * 40); \
        _Pragma("unroll")                                                      \
        for (int mi = 0; mi < 4; ++mi)                                         \
            _Pragma("unroll")                                                  \
            for (int ni = 0; ni < 4; ++ni)                                     \
                acc[mi][ni] = __builtin_amdgcn_mfma_f32_16x16x32_bf16(         \
                    af[mi], bfr[ni], acc[mi][ni], 0, 0, 0);                    \
        __syncthreads();                                                       \
    }

// generic: C = A * Bt^T (+bias)(+relu), bf16 or f32 out
template<int OUTBF, int ACT>
__global__ __launch_bounds__(256) void gemm_bf16_kernel(
    const ushort* __restrict__ A, const ushort* __restrict__ Bt,
    const float* __restrict__ bias, void* __restrict__ Cout,
    int M, int N, int K) {
    __shared__ ushort As[128 * 40];
    __shared__ ushort Bs[128 * 40];
    int m0 = blockIdx.y * 128, n0 = blockIdx.x * 128;
    GEMM_BODY(A, Bt, K)
    float* Cf  = (float*)Cout;
    ushort* Cb = (ushort*)Cout;
    #pragma unroll
    for (int ni = 0; ni < 4; ++ni) {
        int cg = n0 + wc * 64 + ni * 16 + fr;
        float bv = bias ? bias[cg] : 0.0f;
        #pragma unroll
        for (int mi = 0; mi < 4; ++mi) {
            int rg = m0 + wr * 64 + mi * 16 + kq * 4;
            #pragma unroll
            for (int r = 0; r < 4; ++r) {
                float v = acc[mi][ni][r] + bv;
                if (ACT) v = fmaxf(v, 0.0f);
                if (OUTBF) Cb[(size_t)(rg + r) * N + cg] = f2b(v);
                else       Cf[(size_t)(rg + r) * N + cg] = v;
            }
        }
    }
}

// QKV: A=cat(4096x1024), Bt=qkv_w^T(3072x1024). Scatter epilogue into
// Qw/Qr [b][n][256][64] (with biases), K/V [b][n][512][64].
__global__ __launch_bounds__(256) void qkv_gemm_kernel(
    const ushort* __restrict__ A, const ushort* __restrict__ Bt,
    const float* __restrict__ rwb, const float* __restrict__ rrb,
    ushort* __restrict__ Qw, ushort* __restrict__ Qr,
    ushort* __restrict__ Kg, ushort* __restrict__ Vg) {
    __shared__ ushort As[128 * 40];
    __shared__ ushort Bs[128 * 40];
    int m0 = blockIdx.y * 128, n0 = blockIdx.x * 128;
    GEMM_BODY(A, Bt, DMODEL)
    #pragma unroll
    for (int ni = 0; ni < 4; ++ni) {
        int e = n0 + wc * 64 + ni * 16 + fr;
        #pragma unroll
        for (int mi = 0; mi < 4; ++mi) {
            int rg = m0 + wr * 64 + mi * 16 + kq * 4;
            #pragma unroll
            for (int r = 0; r < 4; ++r) {
                float v = acc[mi][ni][r];
                int m = rg + r;
                int b_ = m & 7, jr = m >> 3;
                if (e < 1024) {
                    if (m >= 2048) {
                        int n_ = e >> 6, d_ = e & 63, i_ = jr - 256;
                        size_t qa = (((size_t)b_ * 16 + n_) * 256 + i_) * 64 + d_;
                        Qw[qa] = f2b(v + rwb[e]);
                        Qr[qa] = f2b(v + rrb[e]);
                    }
                } else if (e < 2048) {
                    int e2 = e - 1024;
                    int n_ = e2 >> 6, d_ = e2 & 63;
                    Kg[(((size_t)b_ * 16 + n_) * 512 + jr) * 64 + d_] = f2b(v);
                } else {
                    int e2 = e - 2048;
                    int n_ = e2 >> 6, d_ = e2 & 63;
                    Vg[(((size_t)b_ * 16 + n_) * 512 + jr) * 64 + d_] = f2b(v);
                }
            }
        }
    }
}

// r_head_k: A=pos(512x1024), Bt=r_w^T(1024x1024) -> rhkT[n][512][64]
__global__ __launch_bounds__(256) void rhk_gemm_kernel(
    const ushort* __restrict__ A, const ushort* __restrict__ Bt,
    ushort* __restrict__ rhkT) {
    __shared__ ushort As[128 * 40];
    __shared__ ushort Bs[128 * 40];
    int m0 = blockIdx.y * 128, n0 = blockIdx.x * 128;
    GEMM_BODY(A, Bt, DMODEL)
    #pragma unroll
    for (int ni = 0; ni < 4; ++ni) {
        int e = n0 + wc * 64 + ni * 16 + fr;
        int n_ = e >> 6, d_ = e & 63;
        #pragma unroll
        for (int mi = 0; mi < 4; ++mi) {
            int rg = m0 + wr * 64 + mi * 16 + kq * 4;
            #pragma unroll
            for (int r = 0; r < 4; ++r)
                rhkT[((size_t)n_ * 512 + (rg + r)) * 64 + d_] = f2b(acc[mi][ni][r]);
        }
    }
}

// BDfull per (b,n): Qr(256x64) @ rhkT_n(512x64)^T, rel-shift in epilogue:
// element (i, rr) -> BD[i][j = rr + i - 255] if 0<=j<512
__global__ __launch_bounds__(256) void bd_gemm_kernel(
    const ushort* __restrict__ QrAll, const ushort* __restrict__ rhkT,
    ushort* __restrict__ BDs) {
    __shared__ ushort As[128 * 40];
    __shared__ ushort Bs[128 * 40];
    int batch = blockIdx.z;                    // b*16+n
    const ushort* A  = QrAll + (size_t)batch * (256 * 64);
    const ushort* Bt = rhkT + (size_t)(batch & 15) * (512 * 64);
    ushort* BDb = BDs + (size_t)batch * (256 * 512);
    int m0 = blockIdx.y * 128, n0 = blockIdx.x * 128;
    GEMM_BODY(A, Bt, 64)
    #pragma unroll
    for (int ni = 0; ni < 4; ++ni) {
        int rr = n0 + wc * 64 + ni * 16 + fr;
        #pragma unroll
        for (int mi = 0; mi < 4; ++mi) {
            int rg = m0 + wr * 64 + mi * 16 + kq * 4;
            #pragma unroll
            for (int r = 0; r < 4; ++r) {
                int i = rg + r;
                int j = rr + i - 255;
                if ((unsigned)j < 512u)
                    BDb[(size_t)i * 512 + j] = f2b(acc[mi][ni][r]);
            }
        }
    }
}

// ---------------- fused flash attention ----------------
// grid (4 qtiles, 8 b, 16 n); 4 waves x 16 q-rows; KV tiles of 64.
__global__ __launch_bounds__(256) void fused_attn_kernel(
    const ushort* __restrict__ Qw, const ushort* __restrict__ Kg,
    const ushort* __restrict__ Vg, const ushort* __restrict__ BDs,
    ushort* __restrict__ vec) {
    __shared__ ushort Ks[64 * 72];
    __shared__ ushort Vt[64 * 72];
    __shared__ ushort Pl[4][16 * 72];
    const int qt = blockIdx.x, b = blockIdx.y, n = blockIdx.z;
    const int tid = threadIdx.x, wv = tid >> 6, lane = tid & 63;
    const int fr = lane & 15, kq = lane >> 4;
    const int q0 = qt * 64;
    const size_t bn = (size_t)b * 16 + n;
    const ushort* Qb  = Qw + bn * 256 * 64;
    const ushort* Kb  = Kg + bn * 512 * 64;
    const ushort* Vb  = Vg + bn * 512 * 64;
    const ushort* BDb = BDs + bn * 256 * 512;
    // Q fragments (held across the whole loop)
    bf16x8 aq0, aq1;
    {
        const ushort* qp = Qb + (size_t)(q0 + wv * 16 + fr) * 64 + kq * 8;
        aq0 = *(const bf16x8*)qp;
        aq1 = *(const bf16x8*)(qp + 32);
    }
    f32x4 O[4] = {};
    float m_r[4], l_r[4];
    #pragma unroll
    for (int r = 0; r < 4; ++r) { m_r[r] = -INFINITY; l_r[r] = 0.0f; }
    const int NT = qt + 5;
    const int krow = tid >> 2, kseg = tid & 3;
    const int vrow = tid & 63, vseg0 = tid >> 6;
    for (int jt = 0; jt < NT; ++jt) {
        __syncthreads();
        // stage K tile [j][d], rows padded to 72 shorts
        {
            const ushort* src = Kb + (size_t)(jt * 64 + krow) * 64 + kseg * 16;
            *(float4*)&Ks[krow * 72 + kseg * 16]     = *(const float4*)src;
            *(float4*)&Ks[krow * 72 + kseg * 16 + 8] = *(const float4*)(src + 8);
        }
        // stage V transposed: Vt[d][j]
        #pragma unroll
        for (int it = 0; it < 2; ++it) {
            int seg = vseg0 + it * 4;
            const ushort* src = Vb + (size_t)(jt * 64 + vrow) * 64 + seg * 8;
            bf16x8 v = *(const bf16x8*)src;
            #pragma unroll
            for (int q = 0; q < 8; ++q)
                Vt[(seg * 8 + q) * 72 + vrow] = (ushort)v[q];
        }
        __syncthreads();
        // S = Qw · K^T (16 x 64)
        f32x4 S[4] = {};
        #pragma unroll
        for (int cb = 0; cb < 4; ++cb) {
            const ushort* kp = &Ks[(cb * 16 + fr) * 72 + kq * 8];
            bf16x8 b0 = *(const bf16x8*)kp;
            bf16x8 b1 = *(const bf16x8*)(kp + 32);
            S[cb] = __builtin_amdgcn_mfma_f32_16x16x32_bf16(aq0, b0, S[cb], 0, 0, 0);
            S[cb] = __builtin_amdgcn_mfma_f32_16x16x32_bf16(aq1, b1, S[cb], 0, 0, 0);
        }
        // + BD, scale, mask
        #pragma unroll
        for (int cb = 0; cb < 4; ++cb) {
            int j = jt * 64 + cb * 16 + fr;
            #pragma unroll
            for (int r = 0; r < 4; ++r) {
                int i = q0 + wv * 16 + kq * 4 + r;
                float bd = b2f(BDb[(size_t)i * 512 + j]);
                float s = (S[cb][r] + bd) * 0.125f;
                S[cb][r] = (j <= i + 256) ? s : -1e30f;
            }
        }
        // online softmax (row groups: 16 fr-lanes share a row)
        float sc[4];
        #pragma unroll
        for (int r = 0; r < 4; ++r) {
            float t = fmaxf(fmaxf(S[0][r], S[1][r]), fmaxf(S[2][r], S[3][r]));
            t = fmaxf(t, __shfl_xor(t, 1));
            t = fmaxf(t, __shfl_xor(t, 2));
            t = fmaxf(t, __shfl_xor(t, 4));
            t = fmaxf(t, __shfl_xor(t, 8));
            float mn = fmaxf(m_r[r], t);
            sc[r] = __expf(m_r[r] - mn);
            m_r[r] = mn;
        }
        float ts[4] = {0.0f, 0.0f, 0.0f, 0.0f};
        #pragma unroll
        for (int cb = 0; cb < 4; ++cb)
            #pragma unroll
            for (int r = 0; r < 4; ++r) {
                float p = __expf(S[cb][r] - m_r[r]);
                S[cb][r] = p;
                ts[r] += p;
            }
        #pragma unroll
        for (int r = 0; r < 4; ++r) {
            float t = ts[r];
            t += __shfl_xor(t, 1);
            t += __shfl_xor(t, 2);
            t += __shfl_xor(t, 4);
            t += __shfl_xor(t, 8);
            l_r[r] = l_r[r] * sc[r] + t;
            #pragma unroll
            for (int ob = 0; ob < 4; ++ob) O[ob][r] *= sc[r];
        }
        // P -> LDS (per-wave buffer), then read as A-fragments
        ushort* P = &Pl[wv][0];
        #pragma unroll
        for (int cb = 0; cb < 4; ++cb)
            #pragma unroll
            for (int r = 0; r < 4; ++r)
                P[(kq * 4 + r) * 72 + cb * 16 + fr] = f2b(S[cb][r]);
        asm volatile("s_waitcnt lgkmcnt(0)" ::: "memory");
        bf16x8 pa0 = *(const bf16x8*)&P[fr * 72 + kq * 8];
        bf16x8 pa1 = *(const bf16x8*)&P[fr * 72 + 32 + kq * 8];
        // O += P · V
        #pragma unroll
        for (int ob = 0; ob < 4; ++ob) {
            const ushort* vp = &Vt[(ob * 16 + fr) * 72 + kq * 8];
            bf16x8 v0 = *(const bf16x8*)vp;
            bf16x8 v1 = *(const bf16x8*)(vp + 32);
            O[ob] = __builtin_amdgcn_mfma_f32_16x16x32_bf16(pa0, v0, O[ob], 0, 0, 0);
            O[ob] = __builtin_amdgcn_mfma_f32_16x16x32_bf16(pa1, v1, O[ob], 0, 0, 0);
        }
    }
    // epilogue: vec[(i*8+b)][n*64+d]
    #pragma unroll
    for (int r = 0; r < 4; ++r) {
        float inv = 1.0f / l_r[r];
        int i = q0 + wv * 16 + kq * 4 + r;
        size_t base = ((size_t)i * 8 + b) * 1024 + n * 64;
        #pragma unroll
        for (int ob = 0; ob < 4; ++ob)
            vec[base + ob * 16 + fr] = f2b(O[ob][r] * inv);
    }
}

// logits GEMM + fused per-token (max, sumexp) over the 128-vocab tile.
__global__ __launch_bounds__(256) void logits_lse_kernel(
    const ushort* __restrict__ A, const ushort* __restrict__ Bt,
    const float* __restrict__ ob, float* __restrict__ pmax, float* __restrict__ psum) {
    __shared__ ushort As[128 * 40];
    __shared__ ushort Bs[128 * 40];
    __shared__ float redm[2][128], reds[2][128];
    int m0 = blockIdx.x * 128;   // vocab
    int n0 = blockIdx.y * 128;   // tokens
    GEMM_BODY(A, Bt, DMODEL)
    int t0 = n0;
    #pragma unroll
    for (int ni = 0; ni < 4; ++ni) {
        float vals[16];
        float vmax = -1e30f;
        #pragma unroll
        for (int mi = 0; mi < 4; ++mi) {
            int rg = m0 + wr * 64 + mi * 16 + kq * 4;
            float4 ob4 = *(const float4*)&ob[rg];
            float o4[4] = {ob4.x, ob4.y, ob4.z, ob4.w};
            #pragma unroll
            for (int r = 0; r < 4; ++r) {
                float v = acc[mi][ni][r] + o4[r];
                vals[mi * 4 + r] = v;
                vmax = fmaxf(vmax, v);
            }
        }
        vmax = fmaxf(vmax, __shfl_xor(vmax, 16));
        vmax = fmaxf(vmax, __shfl_xor(vmax, 32));
        float s = 0.0f;
        #pragma unroll
        for (int q = 0; q < 16; ++q) s += __expf(vals[q] - vmax);
        s += __shfl_xor(s, 16);
        s += __shfl_xor(s, 32);
        if (kq == 0) {
            redm[wr][wc * 64 + ni * 16 + fr] = vmax;
            reds[wr][wc * 64 + ni * 16 + fr] = s;
        }
    }
    __syncthreads();
    if (tid < 128) {
        float ma = redm[0][tid], mb = redm[1][tid];
        float m = fmaxf(ma, mb);
        float s = reds[0][tid] * __expf(ma - m) + reds[1][tid] * __expf(mb - m);
        pmax[(size_t)(t0 + tid) * VTILES + blockIdx.x] = m;
        psum[(size_t)(t0 + tid) * VTILES + blockIdx.x] = s;
    }
}

// h = LN(x + h)*g + b, writes fp32 h and bf16 copy
__global__ __launch_bounds__(256) void ln_kernel(const float* __restrict__ x,
    float* __restrict__ h, const float* __restrict__ g, const float* __restrict__ bb,
    ushort* __restrict__ hb) {
    int t = blockIdx.x, tid = threadIdx.x;
    __shared__ float rs[256], rq[256];
    float v[4];
    float s = 0.0f, sq = 0.0f;
    for (int u = 0; u < 4; ++u) {
        int d = tid + u * 256;
        float val = x[(size_t)t * DMODEL + d] + h[(size_t)t * DMODEL + d];
        v[u] = val; s += val; sq += val * val;
    }
    rs[tid] = s; rq[tid] = sq;
    __syncthreads();
    for (int st = 128; st > 0; st >>= 1) {
        if (tid < st) { rs[tid] += rs[tid + st]; rq[tid] += rq[tid + st]; }
        __syncthreads();
    }
    float mean = rs[0] * (1.0f / DMODEL);
    float var = rq[0] * (1.0f / DMODEL) - mean * mean;
    float r = rsqrtf(var + 1e-3f);
    for (int u = 0; u < 4; ++u) {
        int d = tid + u * 256;
        float o = (v[u] - mean) * r * g[d] + bb[d];
        h[(size_t)t * DMODEL + d] = o;
        hb[(size_t)t * DMODEL + d] = f2b(o);
    }
}

// ---------------- final loss pieces ----------------

__global__ __launch_bounds__(64) void tgt_kernel(const float* __restrict__ h,
    const float* __restrict__ W, const float* __restrict__ ob,
    const int* __restrict__ target, float* __restrict__ tgt) {
    int t = blockIdx.x;
    int lane = threadIdx.x;
    int row = target[t];
    const float* hp = h + (size_t)t * DMODEL;
    const float* wp = W + (size_t)row * DMODEL;
    float s = 0.0f;
    for (int d = lane; d < DMODEL; d += 64) s += hp[d] * wp[d];
    for (int o = 32; o > 0; o >>= 1) s += __shfl_down(s, o);
    if (lane == 0) tgt[t] = s + ob[row];
}

__global__ __launch_bounds__(64) void lse_kernel(const float* __restrict__ pmax,
    const float* __restrict__ psum, float* __restrict__ lse) {
    int t = blockIdx.x;
    int lane = threadIdx.x;
    const float* pm = pmax + (size_t)t * VTILES;
    const float* ps = psum + (size_t)t * VTILES;
    float m = -1e30f;
    for (int c = lane; c < VTILES; c += 64) m = fmaxf(m, pm[c]);
    for (int o = 32; o > 0; o >>= 1) m = fmaxf(m, __shfl_xor(m, o));
    float s = 0.0f;
    for (int c = lane; c < VTILES; c += 64) s += ps[c] * expf(pm[c] - m);
    for (int o = 32; o > 0; o >>= 1) s += __shfl_xor(s, o);
    if (lane == 0) lse[t] = m + logf(s);
}

__global__ __launch_bounds__(256) void loss_kernel(const float* __restrict__ lse,
    const float* __restrict__ tgt, const float* __restrict__ vm, float* __restrict__ out) {
    __shared__ float red[256];
    int tid = threadIdx.x;
    float s = 0.0f;
    for (int t = tid; t < NTOK; t += 256) s += (lse[t] - tgt[t]) * vm[t];
    red[tid] = s;
    __syncthreads();
    for (int st = 128; st > 0; st >>= 1) {
        if (tid < st) red[tid] += red[tid + st];
        __syncthreads();
    }
    if (tid == 0) out[0] = red[0] * (1.0f / NTOK);
}

// ---------------- launch ----------------
extern "C" void kernel_launch(void* const* d_in, const int* in_sizes, int n_in,
                              void* d_out, int out_size, void* d_ws, size_t ws_size,
                              hipStream_t stream) {
    const int*   dec_inp   = (const int*)  d_in[0];
    const int*   target    = (const int*)  d_in[1];
    const float* valid     = (const float*)d_in[2];
    const float* mems      = (const float*)d_in[3];
    const float* vocab_emb = (const float*)d_in[4];
    const float* out_w     = (const float*)d_in[5];
    const float* out_b     = (const float*)d_in[6];
    const float* qkv_w     = (const float*)d_in[7];
    const float* r_w       = (const float*)d_in[8];
    const float* o_w       = (const float*)d_in[9];
    const float* ln1_g     = (const float*)d_in[10];
    const float* ln1_b     = (const float*)d_in[11];
    const float* ff_w1     = (const float*)d_in[12];
    const float* ff_b1     = (const float*)d_in[13];
    const float* ff_w2     = (const float*)d_in[14];
    const float* ff_b2     = (const float*)d_in[15];
    const float* ln2_g     = (const float*)d_in[16];
    const float* ln2_b     = (const float*)d_in[17];
    const float* r_w_bias  = (const float*)d_in[18];
    const float* r_r_bias  = (const float*)d_in[19];

    float* ws = (float*)d_ws;
    float*  h      = ws + O_H;
    ushort* hbf    = (ushort*)(ws + O_HBF);
    ushort* posbf  = (ushort*)(ws + O_POSBF);
    ushort* qkvt   = (ushort*)(ws + O_QKVT);
    ushort* rwt    = (ushort*)(ws + O_RWT);
    ushort* owt    = (ushort*)(ws + O_OWT);
    ushort* ffw1t  = (ushort*)(ws + O_FFW1T);
    ushort* ffw2t  = (ushort*)(ws + O_FFW2T);
    ushort* catbf  = (ushort*)(ws + O_CATBF);
    ushort* qwv    = (ushort*)(ws + O_QW);
    ushort* qrv    = (ushort*)(ws + O_QR);
    ushort* kg     = (ushort*)(ws + O_KG);
    ushort* vg     = (ushort*)(ws + O_VG);
    ushort* rhkT   = (ushort*)(ws + O_RHKT);
    ushort* vecbf  = (ushort*)(ws + O_VECBF);
    float*  tattn  = ws + O_TATTN;
    ushort* bds    = (ushort*)(ws + O_BDS);
    ushort* t1bf   = (ushort*)(ws + O_T1BF);
    float*  t2     = ws + O_T2;
    ushort* outwbf = (ushort*)(ws + O_OUTWBF);
    float*  pmax   = ws + O_PMAX;
    float*  psum   = ws + O_PSUM;
    float*  lse    = ws + O_LSE;
    float*  tgt    = ws + O_TGT;

    // ---- weight prep (transpose + bf16) ----
    for (int l = 0; l < NLAYER; ++l) {
        transpose_bf16_kernel<<<dim3(96, 32), 256, 0, stream>>>(
            qkv_w + (size_t)l * DMODEL * 3072, qkvt + (size_t)l * 3072 * DMODEL, DMODEL, 3072);
        transpose_bf16_kernel<<<dim3(32, 32), 256, 0, stream>>>(
            r_w + (size_t)l * DMODEL * DMODEL, rwt + (size_t)l * DMODEL * DMODEL, DMODEL, DMODEL);
        transpose_bf16_kernel<<<dim3(32, 32), 256, 0, stream>>>(
            o_w + (size_t)l * DMODEL * DMODEL, owt + (size_t)l * DMODEL * DMODEL, DMODEL, DMODEL);
        transpose_bf16_kernel<<<dim3(128, 32), 256, 0, stream>>>(
            ff_w1 + (size_t)l * DMODEL * DINNER, ffw1t + (size_t)l * DINNER * DMODEL, DMODEL, DINNER);
        transpose_bf16_kernel<<<dim3(32, 128), 256, 0, stream>>>(
            ff_w2 + (size_t)l * DINNER * DMODEL, ffw2t + (size_t)l * DMODEL * DINNER, DINNER, DMODEL);
    }
    embed_kernel<<<NTOK, 256, 0, stream>>>(dec_inp, vocab_emb, h);
    posemb_kernel<<<KLEN, 256, 0, stream>>>(posbf);

    for (int l = 0; l < NLAYER; ++l) {
        const float* mem_l = mems + (size_t)l * MLEN * BSZ * DMODEL;
        cat_bf16_kernel<<<4096, 256, 0, stream>>>(mem_l, h, catbf);
        // qkv + scatter into Q/K/V layouts
        qkv_gemm_kernel<<<dim3(24, 32), 256, 0, stream>>>(
            catbf, qkvt + (size_t)l * 3072 * DMODEL, r_w_bias, r_r_bias, qwv, qrv, kg, vg);
        // r_head_k -> rhkT[n][512][64]
        rhk_gemm_kernel<<<dim3(8, 4), 256, 0, stream>>>(
            posbf, rwt + (size_t)l * DMODEL * DMODEL, rhkT);
        // BD with rel-shift epilogue
        bd_gemm_kernel<<<dim3(4, 2, 128), 256, 0, stream>>>(qrv, rhkT, bds);
        // fused attention
        fused_attn_kernel<<<dim3(4, BSZ, NHEAD), 256, 0, stream>>>(qwv, kg, vg, bds, vecbf);
        // attn out proj -> f32
        gemm_bf16_kernel<0, 0><<<dim3(8, 16), 256, 0, stream>>>(
            vecbf, owt + (size_t)l * DMODEL * DMODEL, nullptr, tattn, NTOK, DMODEL, DMODEL);
        ln_kernel<<<NTOK, 256, 0, stream>>>(tattn, h, ln1_g + l * DMODEL, ln1_b + l * DMODEL, hbf);
        // ff1 = relu(h @ ff_w1 + b1) -> bf16
        gemm_bf16_kernel<1, 1><<<dim3(32, 16), 256, 0, stream>>>(
            hbf, ffw1t + (size_t)l * DINNER * DMODEL, ff_b1 + (size_t)l * DINNER, t1bf, NTOK, DINNER, DMODEL);
        // ff2 = relu(t1 @ ff_w2 + b2) -> f32
        gemm_bf16_kernel<0, 1><<<dim3(8, 16), 256, 0, stream>>>(
            t1bf, ffw2t + (size_t)l * DMODEL * DINNER, ff_b2 + (size_t)l * DMODEL, t2, NTOK, DMODEL, DINNER);
        ln_kernel<<<NTOK, 256, 0, stream>>>(t2, h, ln2_g + l * DMODEL, ln2_b + l * DMODEL, hbf);
    }

    // ---- final: logits LSE + target + combine + mean ----
    convert_bf16_kernel<<<32000, 256, 0, stream>>>(out_w, outwbf);
    logits_lse_kernel<<<dim3(VTILES, NTOK / 128), 256, 0, stream>>>(
        outwbf, hbf, out_b, pmax, psum);
    tgt_kernel<<<NTOK, 64, 0, stream>>>(h, out_w, out_b, target, tgt);
    lse_kernel<<<NTOK, 64, 0, stream>>>(pmax, psum, lse);
    loss_kernel<<<1, 256, 0, stream>>>(lse, tgt, valid, (float*)d_out);
}